// Round 4
// baseline (392.575 us; speedup 1.0000x reference)
//
#include <hip/hip_runtime.h>
#include <hip/hip_bf16.h>
#include <math.h>

#define BATCH 16384

typedef unsigned short u16;
typedef short bf16x8 __attribute__((ext_vector_type(8)));
typedef float f32x4 __attribute__((ext_vector_type(4)));
typedef u16 u16x8 __attribute__((ext_vector_type(8)));
typedef u16 u16x4 __attribute__((ext_vector_type(4)));

__constant__ int PERMS_C[6][3] = {{0,1,2},{0,2,1},{1,0,2},{1,2,0},{2,0,1},{2,1,0}};

__device__ inline float bf2f(u16 u) {
    unsigned int x = ((unsigned int)u) << 16;
    float f; __builtin_memcpy(&f, &x, 4); return f;
}
__device__ inline u16 f2bf(float f) {
    __hip_bfloat16 h = __float2bfloat16(f);
    u16 u; __builtin_memcpy(&u, &h, 2); return u;
}
__device__ inline float gelu_exact(float x) {
    return 0.5f * x * (1.0f + erff(x * 0.70710678118654752f));
}

// async global->LDS, 16B per lane, wave-uniform LDS base + lane*16
__device__ inline void gload_lds16(const u16* g, u16* l) {
    __builtin_amdgcn_global_load_lds(
        (const __attribute__((address_space(1))) unsigned int*)g,
        (__attribute__((address_space(3))) unsigned int*)l,
        16, 0, 0);
}

// ---------------------------------------------------------------------------
// prep: convert seq_embed to bf16, build transposed bf16 weight blocks,
// concatenated biases, zero states.
// ---------------------------------------------------------------------------
__global__ __launch_bounds__(256) void prep_kernel(
    const float* __restrict__ seq,
    const float* __restrict__ pw1, const float* __restrict__ pw2,
    const float* __restrict__ fw1, const float* __restrict__ fw2,
    const float* __restrict__ pb1, const float* __restrict__ pb2,
    const float* __restrict__ fb1, const float* __restrict__ fb2,
    u16* __restrict__ sb, u16* __restrict__ W1T, u16* __restrict__ W2T,
    float* __restrict__ bias1, float* __restrict__ bias2,
    float* __restrict__ states)
{
    const int N0 = BATCH * 512;      // seq conversion
    const int N1 = 1024 * 512;       // W1T
    const int N2 = 768 * 512;        // W2T
    const int N3 = 1024;             // bias1
    const int N4 = 768;              // bias2
    const int N5 = BATCH * 18;       // states
    int i = blockIdx.x * 256 + threadIdx.x;
    if (i < N0) { sb[i] = f2bf(seq[i]); return; }
    i -= N0;
    if (i < N1) {
        int n = i >> 9, k = i & 511;
        float v = (n < 512) ? pw1[(size_t)k * 512 + n] : fw1[(size_t)k * 512 + (n - 512)];
        W1T[i] = f2bf(v); return;
    }
    i -= N1;
    if (i < N2) {
        int n = i >> 9, k = i & 511;
        float v = (n < 256) ? pw2[(size_t)k * 256 + n] : fw2[(size_t)k * 512 + (n - 256)];
        W2T[i] = f2bf(v); return;
    }
    i -= N2;
    if (i < N3) { bias1[i] = (i < 512) ? pb1[i] : fb1[i - 512]; return; }
    i -= N3;
    if (i < N4) { bias2[i] = (i < 256) ? pb2[i] : fb2[i - 256]; return; }
    i -= N4;
    if (i < N5) { states[i] = 0.0f; return; }
}

// ---------------------------------------------------------------------------
// bf16 MFMA GEMM: C[M,N](bf16) = act(A[M,K](bf16) @ Bt[N,K]^T + bias)
// 128x128 tile, 4 waves (each a 64x64 quadrant), BK=64, 16x16x32 bf16 MFMA.
// Staging via global_load_lds width=16 into LINEAR [128][64] LDS (required:
// contiguous wave-uniform-base + lane*16 destination). 16-way ds_read bank
// conflict is hidden in this 2-barrier regime (m233/m252; m97 = 874 TF).
// ---------------------------------------------------------------------------
__global__ __launch_bounds__(256) void gemm_bf16(
    const u16* __restrict__ A0, const u16* __restrict__ A1, int lda,
    const u16* __restrict__ Bt, const float* __restrict__ bias,
    u16* __restrict__ C, int M, int N, int K, int n_split, int apply_gelu)
{
    __shared__ __align__(16) u16 As[128 * 64];
    __shared__ __align__(16) u16 Bs[128 * 64];

    const int bm = blockIdx.x * 128;
    const int bn = blockIdx.y * 128;
    const u16* __restrict__ A = (bn < n_split) ? A0 : A1;

    const int tid = threadIdx.x;
    const int wv = tid >> 6;
    const int lane = tid & 63;
    const int wr = wv >> 1;      // 0..1 : row half
    const int wc = wv & 1;       // 0..1 : col half

    // staging geometry: chunk c covers rows c*8..c*8+7, 64 cols, 1KB.
    // lane l -> row c*8 + (l>>3), col (l&7)*8 ; LDS dest = c*1024B + l*16B.
    const int lrow = lane >> 3;
    const int lcol = (lane & 7) << 3;

    f32x4 acc[4][4];
#pragma unroll
    for (int i = 0; i < 4; ++i)
#pragma unroll
        for (int j = 0; j < 4; ++j) acc[i][j] = (f32x4){0.f, 0.f, 0.f, 0.f};

    for (int k0 = 0; k0 < K; k0 += 64) {
#pragma unroll
        for (int q = 0; q < 4; ++q) {
            const int c = wv * 4 + q;
            const int row = c * 8 + lrow;
            gload_lds16(&A[(size_t)(bm + row) * lda + k0 + lcol], &As[c * 512]);
            gload_lds16(&Bt[(size_t)(bn + row) * K + k0 + lcol], &Bs[c * 512]);
        }
        __syncthreads();   // compiler emits vmcnt(0) drain before s_barrier

#pragma unroll
        for (int ks = 0; ks < 64; ks += 32) {
            int kk = ks + (lane >> 4) * 8;
            bf16x8 af[4], bfr[4];
#pragma unroll
            for (int i = 0; i < 4; ++i)
                af[i] = *reinterpret_cast<const bf16x8*>(&As[(wr * 64 + i * 16 + (lane & 15)) * 64 + kk]);
#pragma unroll
            for (int j = 0; j < 4; ++j)
                bfr[j] = *reinterpret_cast<const bf16x8*>(&Bs[(wc * 64 + j * 16 + (lane & 15)) * 64 + kk]);
#pragma unroll
            for (int i = 0; i < 4; ++i)
#pragma unroll
                for (int j = 0; j < 4; ++j)
                    acc[i][j] = __builtin_amdgcn_mfma_f32_16x16x32_bf16(af[i], bfr[j], acc[i][j], 0, 0, 0);
        }
        __syncthreads();
    }

    const int r4 = (lane >> 4) * 4;
    const int cn = lane & 15;
#pragma unroll
    for (int i = 0; i < 4; ++i) {
#pragma unroll
        for (int j = 0; j < 4; ++j) {
            int gcol = bn + wc * 64 + j * 16 + cn;
            float bsv = bias[gcol];
#pragma unroll
            for (int r = 0; r < 4; ++r) {
                int grow = bm + wr * 64 + i * 16 + r4 + r;
                float v = acc[i][j][r] + bsv;
                if (apply_gelu) v = gelu_exact(v);
                C[(size_t)grow * N + gcol] = f2bf(v);
            }
        }
    }
}

// ---------------------------------------------------------------------------
// step_h1: weights-in-registers, row-streaming. Both halves in one launch
// (blockIdx.y = 0 -> pres half [0:512], 1 -> full half [512:1024]).
// ---------------------------------------------------------------------------
template<int NSTATE>
__device__ inline void step_h1_body(
    const u16* __restrict__ Z, const float* __restrict__ wsrc,
    const float* __restrict__ state, const int* __restrict__ perm_idx, int step,
    u16* __restrict__ H1, int colBase)
{
    constexpr int NR = NSTATE + 3;
    const int tid = threadIdx.x;
    const int c64 = tid & 63;          // column chunk
    const int ws = tid >> 6;           // row stream 0..3
    const int col0 = c64 * 8;

    float w[NR][8];
#pragma unroll
    for (int t = 0; t < NR; ++t) {
        float4 a = *reinterpret_cast<const float4*>(&wsrc[(size_t)t * 512 + col0]);
        float4 b = *reinterpret_cast<const float4*>(&wsrc[(size_t)t * 512 + col0 + 4]);
        w[t][0] = a.x; w[t][1] = a.y; w[t][2] = a.z; w[t][3] = a.w;
        w[t][4] = b.x; w[t][5] = b.y; w[t][6] = b.z; w[t][7] = b.w;
    }

    int row = blockIdx.x * 16 + ws;
#pragma unroll 2
    for (int i = 0; i < 4; ++i, row += 4) {
        const int ridx = PERMS_C[perm_idx[row]][step];
        float s0[NSTATE];
        if constexpr (NSTATE == 6) {
            float2 a = *reinterpret_cast<const float2*>(&state[row * 6]);
            float2 b = *reinterpret_cast<const float2*>(&state[row * 6 + 2]);
            float2 c = *reinterpret_cast<const float2*>(&state[row * 6 + 4]);
            s0[0] = a.x; s0[1] = a.y; s0[2] = b.x; s0[3] = b.y; s0[4] = c.x; s0[5] = c.y;
        } else {
            float4 a = *reinterpret_cast<const float4*>(&state[row * 12]);
            float4 b = *reinterpret_cast<const float4*>(&state[row * 12 + 4]);
            float4 c = *reinterpret_cast<const float4*>(&state[row * 12 + 8]);
            s0[0] = a.x; s0[1] = a.y; s0[2]  = a.z; s0[3]  = a.w;
            s0[4] = b.x; s0[5] = b.y; s0[6]  = b.z; s0[7]  = b.w;
            s0[8] = c.x; s0[9] = c.y; s0[10] = c.z; s0[11] = c.w;
        }
        u16x8 z = *reinterpret_cast<const u16x8*>(&Z[(size_t)row * 1024 + colBase + col0]);
        u16x8 o;
#pragma unroll
        for (int e = 0; e < 8; ++e) {
            float d = (ridx == 0) ? w[NSTATE][e]
                    : ((ridx == 1) ? w[NSTATE + 1][e] : w[NSTATE + 2][e]);
#pragma unroll
            for (int t = 0; t < NSTATE; ++t) d += s0[t] * w[t][e];
            o[e] = f2bf(gelu_exact(bf2f(z[e]) + d));
        }
        *reinterpret_cast<u16x8*>(&H1[(size_t)row * 1024 + colBase + col0]) = o;
    }
}

__global__ __launch_bounds__(256) void step_h1_both(
    const u16* __restrict__ Z,
    const float* __restrict__ pw1s, const float* __restrict__ fw1s,
    const float* __restrict__ pres_state, const float* __restrict__ full_state,
    const int* __restrict__ perm_idx, int step, u16* __restrict__ H1)
{
    if (blockIdx.y == 0)
        step_h1_body<6>(Z, pw1s, pres_state, perm_idx, step, H1, 0);
    else
        step_h1_body<12>(Z, fw1s, full_state, perm_idx, step, H1, 512);
}

// ---------------------------------------------------------------------------
// step_head: 16 rows/block, hoisted weights, parallel tails, no atomics.
// ---------------------------------------------------------------------------
__global__ __launch_bounds__(256) void step_head(
    const u16* __restrict__ H2,
    const float* __restrict__ pw3, const float* __restrict__ pb3,
    const float* __restrict__ fw3, const float* __restrict__ fb3,
    const float* __restrict__ freq, const float* __restrict__ presv,
    const float* __restrict__ enrich,
    const int* __restrict__ round_mask, const int* __restrict__ perm_idx, int step,
    float* __restrict__ pres_state, float* __restrict__ full_state,
    float* __restrict__ part, float* __restrict__ out)
{
    const int wid = threadIdx.x >> 6;
    const int lane = threadIdx.x & 63;
    const int row0 = blockIdx.x * 16;

    __shared__ float lg[16][4];

    float4 wp = *reinterpret_cast<const float4*>(&pw3[lane * 4]);
    float4 wa = *reinterpret_cast<const float4*>(&fw3[lane * 16]);
    float4 wb = *reinterpret_cast<const float4*>(&fw3[lane * 16 + 4]);
    float4 wc = *reinterpret_cast<const float4*>(&fw3[lane * 16 + 8]);
    float4 wd = *reinterpret_cast<const float4*>(&fw3[lane * 16 + 12]);

#pragma unroll
    for (int i = 0; i < 4; ++i) {
        const int r = wid * 4 + i;
        const int b = row0 + r;
        const u16* h2 = &H2[(size_t)b * 768];

        u16x4 hp = *reinterpret_cast<const u16x4*>(&h2[lane * 4]);
        float sp = bf2f(hp[0]) * wp.x + bf2f(hp[1]) * wp.y
                 + bf2f(hp[2]) * wp.z + bf2f(hp[3]) * wp.w;

        u16x8 hf = *reinterpret_cast<const u16x8*>(&h2[256 + lane * 8]);
        float h0 = bf2f(hf[0]), h1 = bf2f(hf[1]), h2v = bf2f(hf[2]), h3 = bf2f(hf[3]);
        float h4 = bf2f(hf[4]), h5 = bf2f(hf[5]), h6v = bf2f(hf[6]), h7 = bf2f(hf[7]);
        float sf = h0 * wa.x + h1 * wa.z + h2v * wb.x + h3 * wb.z
                 + h4 * wc.x + h5 * wc.z + h6v * wd.x + h7 * wd.z;
        float se = h0 * wa.y + h1 * wa.w + h2v * wb.y + h3 * wb.w
                 + h4 * wc.y + h5 * wc.w + h6v * wd.y + h7 * wd.w;

        for (int off = 32; off > 0; off >>= 1) {
            sp += __shfl_down(sp, off);
            sf += __shfl_down(sf, off);
            se += __shfl_down(se, off);
        }
        if (lane == 0) { lg[r][0] = sp; lg[r][1] = sf; lg[r][2] = se; }
    }
    __syncthreads();

    float lf = 0.f, bce = 0.f, le = 0.f, mm = 0.f;
    if (wid == 0) {
        if (lane < 16) {
            const int b = row0 + lane;
            float logit = lg[lane][0] + pb3[0];
            float pf    = lg[lane][1] + fb3[0];
            float pe    = lg[lane][2] + fb3[1];
            int ridx = PERMS_C[perm_idx[b]][step];
            float gt_f = freq[b * 3 + ridx];
            float gt_p = presv[b * 3 + ridx];
            float gt_e = enrich[b * 3 + ridx];
            float m = (float)round_mask[b * 3 + ridx];
            lf  = (pf - gt_f) * (pf - gt_f) * m;
            bce = (fmaxf(logit, 0.f) - logit * gt_p + log1pf(expf(-fabsf(logit)))) * m;
            le  = (pe - gt_e) * (pe - gt_e) * m;
            mm  = m;
            bool msk = m > 0.5f;
            float act_f = msk ? fminf(fmaxf(pf, -10.f), 10.f) : gt_f;
            float act_p = msk ? 1.f / (1.f + expf(-logit)) : gt_p;
            float act_e = msk ? fminf(fmaxf(pe, -100.f), 100.f) : gt_e;
            pres_state[b * 6 + ridx * 2 + 0] = act_p;
            pres_state[b * 6 + ridx * 2 + 1] = 1.f;
            full_state[b * 12 + ridx * 4 + 0] = act_f;
            full_state[b * 12 + ridx * 4 + 1] = act_p;
            full_state[b * 12 + ridx * 4 + 2] = act_e;
            full_state[b * 12 + ridx * 4 + 3] = 1.f;
            out[3 + b * 3 + ridx] = act_f;
            out[3 + 3 * BATCH + b * 3 + ridx] = act_p;
            out[3 + 6 * BATCH + b * 3 + ridx] = act_e;
        }
        for (int off = 8; off > 0; off >>= 1) {
            lf  += __shfl_down(lf, off);
            bce += __shfl_down(bce, off);
            le  += __shfl_down(le, off);
            mm  += __shfl_down(mm, off);
        }
        if (lane == 0) {
            float4 v; v.x = lf; v.y = bce; v.z = le; v.w = mm;
            *reinterpret_cast<float4*>(&part[blockIdx.x * 4]) = v;
        }
    }
}

#define HEAD_BLOCKS (BATCH / 16)

__global__ __launch_bounds__(256) void finalize_kernel(
    const float* __restrict__ part, float* __restrict__ out)
{
    __shared__ float red[4][4];
    const int nslots = 3 * HEAD_BLOCKS;
    float a0 = 0.f, a1 = 0.f, a2 = 0.f, a3 = 0.f;
    for (int j = threadIdx.x; j < nslots; j += 256) {
        float4 v = *reinterpret_cast<const float4*>(&part[j * 4]);
        a0 += v.x; a1 += v.y; a2 += v.z; a3 += v.w;
    }
    for (int off = 32; off > 0; off >>= 1) {
        a0 += __shfl_down(a0, off);
        a1 += __shfl_down(a1, off);
        a2 += __shfl_down(a2, off);
        a3 += __shfl_down(a3, off);
    }
    const int wid = threadIdx.x >> 6, lane = threadIdx.x & 63;
    if (lane == 0) { red[wid][0] = a0; red[wid][1] = a1; red[wid][2] = a2; red[wid][3] = a3; }
    __syncthreads();
    if (threadIdx.x == 0) {
        float s0 = 0.f, s1 = 0.f, s2 = 0.f, s3 = 0.f;
#pragma unroll
        for (int w2 = 0; w2 < 4; ++w2) {
            s0 += red[w2][0]; s1 += red[w2][1]; s2 += red[w2][2]; s3 += red[w2][3];
        }
        float nm = s3 + 1e-8f;
        out[0] = s0 / nm;
        out[1] = s1 / nm;
        out[2] = s2 / nm;
    }
}

// ---------------------------------------------------------------------------
extern "C" void kernel_launch(void* const* d_in, const int* in_sizes, int n_in,
                              void* d_out, int out_size, void* d_ws, size_t ws_size,
                              hipStream_t stream)
{
    const float* seq       = (const float*)d_in[0];
    const float* freq      = (const float*)d_in[1];
    const float* presv     = (const float*)d_in[2];
    const float* enrich    = (const float*)d_in[3];
    const float* pw1       = (const float*)d_in[4];
    const float* pb1       = (const float*)d_in[5];
    const float* pw2       = (const float*)d_in[6];
    const float* pb2       = (const float*)d_in[7];
    const float* pw3       = (const float*)d_in[8];
    const float* pb3       = (const float*)d_in[9];
    const float* fw1       = (const float*)d_in[10];
    const float* fb1       = (const float*)d_in[11];
    const float* fw2       = (const float*)d_in[12];
    const float* fb2       = (const float*)d_in[13];
    const float* fw3       = (const float*)d_in[14];
    const float* fb3       = (const float*)d_in[15];
    const int*   perm_idx  = (const int*)d_in[16];
    const int*   round_mask= (const int*)d_in[17];
    float* out = (float*)d_out;

    char* w = (char*)d_ws;
    u16* sb  = (u16*)w;  w += (size_t)BATCH * 512 * 2;   // 16 MB
    u16* Z   = (u16*)w;  w += (size_t)BATCH * 1024 * 2;  // 32 MB
    u16* H1  = (u16*)w;  w += (size_t)BATCH * 1024 * 2;  // 32 MB
    u16* H2  = (u16*)w;  w += (size_t)BATCH * 768 * 2;   // 24 MB
    u16* W1T = (u16*)w;  w += (size_t)1024 * 512 * 2;
    u16* W2T = (u16*)w;  w += (size_t)768 * 512 * 2;
    float* bias1 = (float*)w; w += 1024 * 4;
    float* bias2 = (float*)w; w += 768 * 4;
    float* states = (float*)w; w += (size_t)BATCH * 18 * 4;
    float* part   = (float*)w;
    float* pres_state = states;
    float* full_state = states + (size_t)BATCH * 6;

    // prep
    {
        const int total = BATCH * 512 + 1024 * 512 + 768 * 512 + 1024 + 768 + BATCH * 18;
        int grid = (total + 255) / 256;
        prep_kernel<<<grid, 256, 0, stream>>>(seq, pw1, pw2, fw1, fw2, pb1, pb2, fb1, fb2,
                                              sb, W1T, W2T, bias1, bias2, states);
    }

    // Z = seq @ [pw1[:512] | fw1[:512]] + bias1   (M=16384, N=1024, K=512)
    gemm_bf16<<<dim3(BATCH / 128, 1024 / 128), 256, 0, stream>>>(
        sb, sb, 512, W1T, bias1, Z, BATCH, 1024, 512, 1 << 30, 0);

    for (int s = 0; s < 3; ++s) {
        step_h1_both<<<dim3(BATCH / 16, 2), 256, 0, stream>>>(
            Z, pw1 + (size_t)512 * 512, fw1 + (size_t)512 * 512,
            pres_state, full_state, perm_idx, s, H1);

        // H2 = gelu([H1p|H1f] @ [pw2|fw2] + bias2)  (M=16384, N=768, K=512)
        gemm_bf16<<<dim3(BATCH / 128, 768 / 128), 256, 0, stream>>>(
            H1, H1 + 512, 1024, W2T, bias2, H2, BATCH, 768, 512, 256, 1);

        step_head<<<HEAD_BLOCKS, 256, 0, stream>>>(
            H2, pw3, pb3, fw3, fb3, freq, presv, enrich,
            round_mask, perm_idx, s, pres_state, full_state,
            part + (size_t)s * HEAD_BLOCKS * 4, out);
    }

    finalize_kernel<<<1, 256, 0, stream>>>(part, out);
}

// Round 5
// 363.995 us; speedup vs baseline: 1.0785x; 1.0785x over previous
//
#include <hip/hip_runtime.h>
#include <hip/hip_bf16.h>
#include <math.h>

#define BATCH 16384

typedef unsigned short u16;
typedef short bf16x8 __attribute__((ext_vector_type(8)));
typedef float f32x4 __attribute__((ext_vector_type(4)));
typedef u16 u16x8 __attribute__((ext_vector_type(8)));
typedef u16 u16x4 __attribute__((ext_vector_type(4)));

__constant__ int PERMS_C[6][3] = {{0,1,2},{0,2,1},{1,0,2},{1,2,0},{2,0,1},{2,1,0}};

__device__ inline float bf2f(u16 u) {
    unsigned int x = ((unsigned int)u) << 16;
    float f; __builtin_memcpy(&f, &x, 4); return f;
}
__device__ inline u16 f2bf(float f) {
    __hip_bfloat16 h = __float2bfloat16(f);
    u16 u; __builtin_memcpy(&u, &h, 2); return u;
}
__device__ inline float gelu_exact(float x) {
    return 0.5f * x * (1.0f + erff(x * 0.70710678118654752f));
}

// async global->LDS, 16B per lane, wave-uniform LDS base + lane*16
__device__ inline void gload_lds16(const u16* g, u16* l) {
    __builtin_amdgcn_global_load_lds(
        (const __attribute__((address_space(1))) unsigned int*)g,
        (__attribute__((address_space(3))) unsigned int*)l,
        16, 0, 0);
}

// ---------------------------------------------------------------------------
// prep: convert seq_embed to bf16, build transposed bf16 weight blocks,
// concatenated biases, zero states.
// ---------------------------------------------------------------------------
__global__ __launch_bounds__(256) void prep_kernel(
    const float* __restrict__ seq,
    const float* __restrict__ pw1, const float* __restrict__ pw2,
    const float* __restrict__ fw1, const float* __restrict__ fw2,
    const float* __restrict__ pb1, const float* __restrict__ pb2,
    const float* __restrict__ fb1, const float* __restrict__ fb2,
    u16* __restrict__ sb, u16* __restrict__ W1T, u16* __restrict__ W2T,
    float* __restrict__ bias1, float* __restrict__ bias2,
    float* __restrict__ states)
{
    const int N0 = BATCH * 512;      // seq conversion
    const int N1 = 1024 * 512;       // W1T
    const int N2 = 768 * 512;        // W2T
    const int N3 = 1024;             // bias1
    const int N4 = 768;              // bias2
    const int N5 = BATCH * 18;       // states
    int i = blockIdx.x * 256 + threadIdx.x;
    if (i < N0) { sb[i] = f2bf(seq[i]); return; }
    i -= N0;
    if (i < N1) {
        int n = i >> 9, k = i & 511;
        float v = (n < 512) ? pw1[(size_t)k * 512 + n] : fw1[(size_t)k * 512 + (n - 512)];
        W1T[i] = f2bf(v); return;
    }
    i -= N1;
    if (i < N2) {
        int n = i >> 9, k = i & 511;
        float v = (n < 256) ? pw2[(size_t)k * 256 + n] : fw2[(size_t)k * 512 + (n - 256)];
        W2T[i] = f2bf(v); return;
    }
    i -= N2;
    if (i < N3) { bias1[i] = (i < 512) ? pb1[i] : fb1[i - 512]; return; }
    i -= N3;
    if (i < N4) { bias2[i] = (i < 256) ? pb2[i] : fb2[i - 256]; return; }
    i -= N4;
    if (i < N5) { states[i] = 0.0f; return; }
}

// ---------------------------------------------------------------------------
// bf16 MFMA GEMM, 2-phase double-buffered pipeline.
// C[M,N](bf16) = act(A[M,K](bf16) @ Bt[N,K]^T + bias)
// 128x128 block tile, 4 waves (64x64 each), BK=32, dbuf LDS (32KB).
// Per iter: STAGE(next buf) -> s_waitcnt vmcnt(4) (next-tile loads stay in
// flight) -> raw s_barrier (no compiler vmcnt(0) drain) -> ds_read+MFMA ->
// raw s_barrier. XOR swizzle via pre-swizzled global SOURCE (linear LDS dest,
// rule #21): slot s_g = s ^ ((row>>1)&3) -> read conflicts 8-way -> 2-way (free).
// Optional fused epilogue: emit H1 step-0 (= gelu(Z + onehot row), state==0).
// ---------------------------------------------------------------------------
__global__ __launch_bounds__(256) void gemm_bf16(
    const u16* __restrict__ A0, const u16* __restrict__ A1, int lda,
    const u16* __restrict__ Bt, const float* __restrict__ bias,
    u16* __restrict__ C, int M, int N, int K, int n_split, int apply_gelu,
    const float* __restrict__ ohp, const float* __restrict__ ohf,
    const int* __restrict__ perm, u16* __restrict__ H1out)
{
    __shared__ __align__(16) u16 As[2][128 * 32];
    __shared__ __align__(16) u16 Bs[2][128 * 32];

    const int bm = blockIdx.x * 128;
    const int bn = blockIdx.y * 128;
    const u16* __restrict__ A = (bn < n_split) ? A0 : A1;

    const int tid = threadIdx.x;
    const int wv = tid >> 6;
    const int lane = tid & 63;
    const int wr = wv >> 1;      // 0..1 : row half
    const int wc = wv & 1;       // 0..1 : col half

    // staging: chunk c = 16 rows x 32 cols (1KB). lane l -> row c*16+(l>>2),
    // global col slot sg = (l&3) ^ ((l>>3)&3)  [inverse swizzle on source]
    const int srow = lane >> 2;
    const int scol = ((lane & 3) ^ ((lane >> 3) & 3)) << 3;

    f32x4 acc[4][4];
#pragma unroll
    for (int i = 0; i < 4; ++i)
#pragma unroll
        for (int j = 0; j < 4; ++j) acc[i][j] = (f32x4){0.f, 0.f, 0.f, 0.f};

    const int NT = K >> 5;   // BK=32 tiles

#define STAGE(buf, k0)                                                         \
    {                                                                          \
        _Pragma("unroll")                                                      \
        for (int q = 0; q < 2; ++q) {                                          \
            const int c = wv * 2 + q;                                          \
            const int row = c * 16 + srow;                                     \
            gload_lds16(&A[(size_t)(bm + row) * lda + (k0) + scol],            \
                        &As[buf][c * 512]);                                    \
            gload_lds16(&Bt[(size_t)(bn + row) * K + (k0) + scol],             \
                        &Bs[buf][c * 512]);                                    \
        }                                                                      \
    }

    STAGE(0, 0);

    // swizzled read col (u16 units): slot (lane>>4) ^ ((lane>>1)&3), 8 u16 each
    const int kkr = (((lane >> 4) ^ ((lane >> 1) & 3)) << 3);
    const int fr = lane & 15;

    for (int t = 0; t < NT; ++t) {
        const int cur = t & 1;
        if (t + 1 < NT) {
            STAGE(cur ^ 1, (t + 1) << 5);
            asm volatile("s_waitcnt vmcnt(4)" ::: "memory");   // cur's 4 loads done
        } else {
            asm volatile("s_waitcnt vmcnt(0)" ::: "memory");
        }
        __builtin_amdgcn_sched_barrier(0);
        __builtin_amdgcn_s_barrier();

        bf16x8 af[4], bfr[4];
#pragma unroll
        for (int i = 0; i < 4; ++i)
            af[i] = *reinterpret_cast<const bf16x8*>(&As[cur][(wr * 64 + i * 16 + fr) * 32 + kkr]);
#pragma unroll
        for (int j = 0; j < 4; ++j)
            bfr[j] = *reinterpret_cast<const bf16x8*>(&Bs[cur][(wc * 64 + j * 16 + fr) * 32 + kkr]);
#pragma unroll
        for (int i = 0; i < 4; ++i)
#pragma unroll
            for (int j = 0; j < 4; ++j)
                acc[i][j] = __builtin_amdgcn_mfma_f32_16x16x32_bf16(af[i], bfr[j], acc[i][j], 0, 0, 0);

        __builtin_amdgcn_sched_barrier(0);
        __builtin_amdgcn_s_barrier();   // protect cur buf before next STAGE
    }
#undef STAGE

    // epilogue: D layout col = lane&15, row = (lane>>4)*4 + reg
    const int r4 = (lane >> 4) * 4;
    const int cn = lane & 15;

    // fused H1 step-0 weights (3 one-hot rows at this block's columns)
    const float* ohb = nullptr;
    float w0[4], w1[4], w2[4];
    if (H1out) {
        ohb = (bn < 512) ? (ohp + bn) : (ohf + (bn - 512));
#pragma unroll
        for (int j = 0; j < 4; ++j) {
            int colw = wc * 64 + j * 16 + cn;
            w0[j] = ohb[colw];
            w1[j] = ohb[512 + colw];
            w2[j] = ohb[1024 + colw];
        }
    }

#pragma unroll
    for (int i = 0; i < 4; ++i) {
        int rsel[4];
        if (H1out) {
#pragma unroll
            for (int r = 0; r < 4; ++r) {
                int grow = bm + wr * 64 + i * 16 + r4 + r;
                rsel[r] = PERMS_C[perm[grow]][0];
            }
        }
#pragma unroll
        for (int j = 0; j < 4; ++j) {
            int gcol = bn + wc * 64 + j * 16 + cn;
            float bsv = bias[gcol];
#pragma unroll
            for (int r = 0; r < 4; ++r) {
                int grow = bm + wr * 64 + i * 16 + r4 + r;
                float v = acc[i][j][r] + bsv;
                if (apply_gelu) v = gelu_exact(v);
                C[(size_t)grow * N + gcol] = f2bf(v);
                if (H1out) {
                    float wv0 = (rsel[r] == 0) ? w0[j] : ((rsel[r] == 1) ? w1[j] : w2[j]);
                    H1out[(size_t)grow * N + gcol] = f2bf(gelu_exact(v + wv0));
                }
            }
        }
    }
}

// ---------------------------------------------------------------------------
// step_h1: weights-in-registers, row-streaming. Both halves in one launch
// (blockIdx.y = 0 -> pres half [0:512], 1 -> full half [512:1024]).
// Used for steps 1,2 (step 0 fused into Z-GEMM epilogue).
// ---------------------------------------------------------------------------
template<int NSTATE>
__device__ inline void step_h1_body(
    const u16* __restrict__ Z, const float* __restrict__ wsrc,
    const float* __restrict__ state, const int* __restrict__ perm_idx, int step,
    u16* __restrict__ H1, int colBase)
{
    constexpr int NR = NSTATE + 3;
    const int tid = threadIdx.x;
    const int c64 = tid & 63;          // column chunk
    const int ws = tid >> 6;           // row stream 0..3
    const int col0 = c64 * 8;

    float w[NR][8];
#pragma unroll
    for (int t = 0; t < NR; ++t) {
        float4 a = *reinterpret_cast<const float4*>(&wsrc[(size_t)t * 512 + col0]);
        float4 b = *reinterpret_cast<const float4*>(&wsrc[(size_t)t * 512 + col0 + 4]);
        w[t][0] = a.x; w[t][1] = a.y; w[t][2] = a.z; w[t][3] = a.w;
        w[t][4] = b.x; w[t][5] = b.y; w[t][6] = b.z; w[t][7] = b.w;
    }

    int row = blockIdx.x * 16 + ws;
#pragma unroll 2
    for (int i = 0; i < 4; ++i, row += 4) {
        const int ridx = PERMS_C[perm_idx[row]][step];
        float s0[NSTATE];
        if constexpr (NSTATE == 6) {
            float2 a = *reinterpret_cast<const float2*>(&state[row * 6]);
            float2 b = *reinterpret_cast<const float2*>(&state[row * 6 + 2]);
            float2 c = *reinterpret_cast<const float2*>(&state[row * 6 + 4]);
            s0[0] = a.x; s0[1] = a.y; s0[2] = b.x; s0[3] = b.y; s0[4] = c.x; s0[5] = c.y;
        } else {
            float4 a = *reinterpret_cast<const float4*>(&state[row * 12]);
            float4 b = *reinterpret_cast<const float4*>(&state[row * 12 + 4]);
            float4 c = *reinterpret_cast<const float4*>(&state[row * 12 + 8]);
            s0[0] = a.x; s0[1] = a.y; s0[2]  = a.z; s0[3]  = a.w;
            s0[4] = b.x; s0[5] = b.y; s0[6]  = b.z; s0[7]  = b.w;
            s0[8] = c.x; s0[9] = c.y; s0[10] = c.z; s0[11] = c.w;
        }
        u16x8 z = *reinterpret_cast<const u16x8*>(&Z[(size_t)row * 1024 + colBase + col0]);
        u16x8 o;
#pragma unroll
        for (int e = 0; e < 8; ++e) {
            float d = (ridx == 0) ? w[NSTATE][e]
                    : ((ridx == 1) ? w[NSTATE + 1][e] : w[NSTATE + 2][e]);
#pragma unroll
            for (int t = 0; t < NSTATE; ++t) d += s0[t] * w[t][e];
            o[e] = f2bf(gelu_exact(bf2f(z[e]) + d));
        }
        *reinterpret_cast<u16x8*>(&H1[(size_t)row * 1024 + colBase + col0]) = o;
    }
}

__global__ __launch_bounds__(256) void step_h1_both(
    const u16* __restrict__ Z,
    const float* __restrict__ pw1s, const float* __restrict__ fw1s,
    const float* __restrict__ pres_state, const float* __restrict__ full_state,
    const int* __restrict__ perm_idx, int step, u16* __restrict__ H1)
{
    if (blockIdx.y == 0)
        step_h1_body<6>(Z, pw1s, pres_state, perm_idx, step, H1, 0);
    else
        step_h1_body<12>(Z, fw1s, full_state, perm_idx, step, H1, 512);
}

// ---------------------------------------------------------------------------
// step_head: 16 rows/block, hoisted weights, parallel tails, no atomics.
// ---------------------------------------------------------------------------
__global__ __launch_bounds__(256) void step_head(
    const u16* __restrict__ H2,
    const float* __restrict__ pw3, const float* __restrict__ pb3,
    const float* __restrict__ fw3, const float* __restrict__ fb3,
    const float* __restrict__ freq, const float* __restrict__ presv,
    const float* __restrict__ enrich,
    const int* __restrict__ round_mask, const int* __restrict__ perm_idx, int step,
    float* __restrict__ pres_state, float* __restrict__ full_state,
    float* __restrict__ part, float* __restrict__ out)
{
    const int wid = threadIdx.x >> 6;
    const int lane = threadIdx.x & 63;
    const int row0 = blockIdx.x * 16;

    __shared__ float lg[16][4];

    float4 wp = *reinterpret_cast<const float4*>(&pw3[lane * 4]);
    float4 wa = *reinterpret_cast<const float4*>(&fw3[lane * 16]);
    float4 wb = *reinterpret_cast<const float4*>(&fw3[lane * 16 + 4]);
    float4 wc = *reinterpret_cast<const float4*>(&fw3[lane * 16 + 8]);
    float4 wd = *reinterpret_cast<const float4*>(&fw3[lane * 16 + 12]);

#pragma unroll
    for (int i = 0; i < 4; ++i) {
        const int r = wid * 4 + i;
        const int b = row0 + r;
        const u16* h2 = &H2[(size_t)b * 768];

        u16x4 hp = *reinterpret_cast<const u16x4*>(&h2[lane * 4]);
        float sp = bf2f(hp[0]) * wp.x + bf2f(hp[1]) * wp.y
                 + bf2f(hp[2]) * wp.z + bf2f(hp[3]) * wp.w;

        u16x8 hf = *reinterpret_cast<const u16x8*>(&h2[256 + lane * 8]);
        float h0 = bf2f(hf[0]), h1 = bf2f(hf[1]), h2v = bf2f(hf[2]), h3 = bf2f(hf[3]);
        float h4 = bf2f(hf[4]), h5 = bf2f(hf[5]), h6v = bf2f(hf[6]), h7 = bf2f(hf[7]);
        float sf = h0 * wa.x + h1 * wa.z + h2v * wb.x + h3 * wb.z
                 + h4 * wc.x + h5 * wc.z + h6v * wd.x + h7 * wd.z;
        float se = h0 * wa.y + h1 * wa.w + h2v * wb.y + h3 * wb.w
                 + h4 * wc.y + h5 * wc.w + h6v * wd.y + h7 * wd.w;

        for (int off = 32; off > 0; off >>= 1) {
            sp += __shfl_down(sp, off);
            sf += __shfl_down(sf, off);
            se += __shfl_down(se, off);
        }
        if (lane == 0) { lg[r][0] = sp; lg[r][1] = sf; lg[r][2] = se; }
    }
    __syncthreads();

    float lf = 0.f, bce = 0.f, le = 0.f, mm = 0.f;
    if (wid == 0) {
        if (lane < 16) {
            const int b = row0 + lane;
            float logit = lg[lane][0] + pb3[0];
            float pf    = lg[lane][1] + fb3[0];
            float pe    = lg[lane][2] + fb3[1];
            int ridx = PERMS_C[perm_idx[b]][step];
            float gt_f = freq[b * 3 + ridx];
            float gt_p = presv[b * 3 + ridx];
            float gt_e = enrich[b * 3 + ridx];
            float m = (float)round_mask[b * 3 + ridx];
            lf  = (pf - gt_f) * (pf - gt_f) * m;
            bce = (fmaxf(logit, 0.f) - logit * gt_p + log1pf(expf(-fabsf(logit)))) * m;
            le  = (pe - gt_e) * (pe - gt_e) * m;
            mm  = m;
            bool msk = m > 0.5f;
            float act_f = msk ? fminf(fmaxf(pf, -10.f), 10.f) : gt_f;
            float act_p = msk ? 1.f / (1.f + expf(-logit)) : gt_p;
            float act_e = msk ? fminf(fmaxf(pe, -100.f), 100.f) : gt_e;
            pres_state[b * 6 + ridx * 2 + 0] = act_p;
            pres_state[b * 6 + ridx * 2 + 1] = 1.f;
            full_state[b * 12 + ridx * 4 + 0] = act_f;
            full_state[b * 12 + ridx * 4 + 1] = act_p;
            full_state[b * 12 + ridx * 4 + 2] = act_e;
            full_state[b * 12 + ridx * 4 + 3] = 1.f;
            out[3 + b * 3 + ridx] = act_f;
            out[3 + 3 * BATCH + b * 3 + ridx] = act_p;
            out[3 + 6 * BATCH + b * 3 + ridx] = act_e;
        }
        for (int off = 8; off > 0; off >>= 1) {
            lf  += __shfl_down(lf, off);
            bce += __shfl_down(bce, off);
            le  += __shfl_down(le, off);
            mm  += __shfl_down(mm, off);
        }
        if (lane == 0) {
            float4 v; v.x = lf; v.y = bce; v.z = le; v.w = mm;
            *reinterpret_cast<float4*>(&part[blockIdx.x * 4]) = v;
        }
    }
}

#define HEAD_BLOCKS (BATCH / 16)

__global__ __launch_bounds__(256) void finalize_kernel(
    const float* __restrict__ part, float* __restrict__ out)
{
    __shared__ float red[4][4];
    const int nslots = 3 * HEAD_BLOCKS;
    float a0 = 0.f, a1 = 0.f, a2 = 0.f, a3 = 0.f;
    for (int j = threadIdx.x; j < nslots; j += 256) {
        float4 v = *reinterpret_cast<const float4*>(&part[j * 4]);
        a0 += v.x; a1 += v.y; a2 += v.z; a3 += v.w;
    }
    for (int off = 32; off > 0; off >>= 1) {
        a0 += __shfl_down(a0, off);
        a1 += __shfl_down(a1, off);
        a2 += __shfl_down(a2, off);
        a3 += __shfl_down(a3, off);
    }
    const int wid = threadIdx.x >> 6, lane = threadIdx.x & 63;
    if (lane == 0) { red[wid][0] = a0; red[wid][1] = a1; red[wid][2] = a2; red[wid][3] = a3; }
    __syncthreads();
    if (threadIdx.x == 0) {
        float s0 = 0.f, s1 = 0.f, s2 = 0.f, s3 = 0.f;
#pragma unroll
        for (int w2 = 0; w2 < 4; ++w2) {
            s0 += red[w2][0]; s1 += red[w2][1]; s2 += red[w2][2]; s3 += red[w2][3];
        }
        float nm = s3 + 1e-8f;
        out[0] = s0 / nm;
        out[1] = s1 / nm;
        out[2] = s2 / nm;
    }
}

// ---------------------------------------------------------------------------
extern "C" void kernel_launch(void* const* d_in, const int* in_sizes, int n_in,
                              void* d_out, int out_size, void* d_ws, size_t ws_size,
                              hipStream_t stream)
{
    const float* seq       = (const float*)d_in[0];
    const float* freq      = (const float*)d_in[1];
    const float* presv     = (const float*)d_in[2];
    const float* enrich    = (const float*)d_in[3];
    const float* pw1       = (const float*)d_in[4];
    const float* pb1       = (const float*)d_in[5];
    const float* pw2       = (const float*)d_in[6];
    const float* pb2       = (const float*)d_in[7];
    const float* pw3       = (const float*)d_in[8];
    const float* pb3       = (const float*)d_in[9];
    const float* fw1       = (const float*)d_in[10];
    const float* fb1       = (const float*)d_in[11];
    const float* fw2       = (const float*)d_in[12];
    const float* fb2       = (const float*)d_in[13];
    const float* fw3       = (const float*)d_in[14];
    const float* fb3       = (const float*)d_in[15];
    const int*   perm_idx  = (const int*)d_in[16];
    const int*   round_mask= (const int*)d_in[17];
    float* out = (float*)d_out;

    char* w = (char*)d_ws;
    u16* sb  = (u16*)w;  w += (size_t)BATCH * 512 * 2;   // 16 MB
    u16* Z   = (u16*)w;  w += (size_t)BATCH * 1024 * 2;  // 32 MB
    u16* H1  = (u16*)w;  w += (size_t)BATCH * 1024 * 2;  // 32 MB
    u16* H2  = (u16*)w;  w += (size_t)BATCH * 768 * 2;   // 24 MB
    u16* W1T = (u16*)w;  w += (size_t)1024 * 512 * 2;
    u16* W2T = (u16*)w;  w += (size_t)768 * 512 * 2;
    float* bias1 = (float*)w; w += 1024 * 4;
    float* bias2 = (float*)w; w += 768 * 4;
    float* states = (float*)w; w += (size_t)BATCH * 18 * 4;
    float* part   = (float*)w;
    float* pres_state = states;
    float* full_state = states + (size_t)BATCH * 6;

    // prep
    {
        const int total = BATCH * 512 + 1024 * 512 + 768 * 512 + 1024 + 768 + BATCH * 18;
        int grid = (total + 255) / 256;
        prep_kernel<<<grid, 256, 0, stream>>>(seq, pw1, pw2, fw1, fw2, pb1, pb2, fb1, fb2,
                                              sb, W1T, W2T, bias1, bias2, states);
    }

    // Z = seq @ [pw1[:512] | fw1[:512]] + bias1, and fused H1 step-0 emission
    gemm_bf16<<<dim3(BATCH / 128, 1024 / 128), 256, 0, stream>>>(
        sb, sb, 512, W1T, bias1, Z, BATCH, 1024, 512, 1 << 30, 0,
        pw1 + (size_t)518 * 512, fw1 + (size_t)524 * 512, perm_idx, H1);

    for (int s = 0; s < 3; ++s) {
        if (s > 0) {
            step_h1_both<<<dim3(BATCH / 16, 2), 256, 0, stream>>>(
                Z, pw1 + (size_t)512 * 512, fw1 + (size_t)512 * 512,
                pres_state, full_state, perm_idx, s, H1);
        }

        // H2 = gelu([H1p|H1f] @ [pw2|fw2] + bias2)  (M=16384, N=768, K=512)
        gemm_bf16<<<dim3(BATCH / 128, 768 / 128), 256, 0, stream>>>(
            H1, H1 + 512, 1024, W2T, bias2, H2, BATCH, 768, 512, 256, 1,
            nullptr, nullptr, nullptr, nullptr);

        step_head<<<HEAD_BLOCKS, 256, 0, stream>>>(
            H2, pw3, pb3, fw3, fb3, freq, presv, enrich,
            round_mask, perm_idx, s, pres_state, full_state,
            part + (size_t)s * HEAD_BLOCKS * 4, out);
    }

    finalize_kernel<<<1, 256, 0, stream>>>(part, out);
}

// Round 6
// 349.755 us; speedup vs baseline: 1.1224x; 1.0407x over previous
//
#include <hip/hip_runtime.h>
#include <hip/hip_bf16.h>
#include <math.h>

#define BATCH 16384

typedef unsigned short u16;
typedef short bf16x8 __attribute__((ext_vector_type(8)));
typedef float f32x4 __attribute__((ext_vector_type(4)));
typedef u16 u16x8 __attribute__((ext_vector_type(8)));
typedef u16 u16x2 __attribute__((ext_vector_type(2)));

__constant__ int PERMS_C[6][3] = {{0,1,2},{0,2,1},{1,0,2},{1,2,0},{2,0,1},{2,1,0}};

__device__ inline float bf2f(u16 u) {
    unsigned int x = ((unsigned int)u) << 16;
    float f; __builtin_memcpy(&f, &x, 4); return f;
}
__device__ inline u16 f2bf(float f) {
    __hip_bfloat16 h = __float2bfloat16(f);
    u16 u; __builtin_memcpy(&u, &h, 2); return u;
}
__device__ inline float gelu_exact(float x) {
    return 0.5f * x * (1.0f + erff(x * 0.70710678118654752f));
}

// async global->LDS, 16B per lane, wave-uniform LDS base + lane*16
__device__ inline void gload_lds16(const u16* g, u16* l) {
    __builtin_amdgcn_global_load_lds(
        (const __attribute__((address_space(1))) unsigned int*)g,
        (__attribute__((address_space(3))) unsigned int*)l,
        16, 0, 0);
}

// ---------------------------------------------------------------------------
// prep: convert seq_embed to bf16, build transposed bf16 weight blocks,
// concatenated biases.
// ---------------------------------------------------------------------------
__global__ __launch_bounds__(256) void prep_kernel(
    const float* __restrict__ seq,
    const float* __restrict__ pw1, const float* __restrict__ pw2,
    const float* __restrict__ fw1, const float* __restrict__ fw2,
    const float* __restrict__ pb1, const float* __restrict__ pb2,
    const float* __restrict__ fb1, const float* __restrict__ fb2,
    u16* __restrict__ sb, u16* __restrict__ W1T, u16* __restrict__ W2T,
    float* __restrict__ bias1, float* __restrict__ bias2)
{
    const int N0 = BATCH * 512;      // seq conversion
    const int N1 = 1024 * 512;       // W1T
    const int N2 = 768 * 512;        // W2T
    const int N3 = 1024;             // bias1
    const int N4 = 768;              // bias2
    int i = blockIdx.x * 256 + threadIdx.x;
    if (i < N0) { sb[i] = f2bf(seq[i]); return; }
    i -= N0;
    if (i < N1) {
        int n = i >> 9, k = i & 511;
        float v = (n < 512) ? pw1[(size_t)k * 512 + n] : fw1[(size_t)k * 512 + (n - 512)];
        W1T[i] = f2bf(v); return;
    }
    i -= N1;
    if (i < N2) {
        int n = i >> 9, k = i & 511;
        float v = (n < 256) ? pw2[(size_t)k * 256 + n] : fw2[(size_t)k * 512 + (n - 256)];
        W2T[i] = f2bf(v); return;
    }
    i -= N2;
    if (i < N3) { bias1[i] = (i < 512) ? pb1[i] : fb1[i - 512]; return; }
    i -= N3;
    if (i < N4) { bias2[i] = (i < 256) ? pb2[i] : fb2[i - 256]; return; }
}

// ---------------------------------------------------------------------------
// bf16 MFMA GEMM (R4 form): C[M,N](bf16) = A[M,K] @ Bt[N,K]^T + bias.
// 128x128 tile, 4 waves, BK=64, global_load_lds staging, linear LDS.
// Used only for Z = seq @ [pw1|fw1] + bias1.
// ---------------------------------------------------------------------------
__global__ __launch_bounds__(256) void gemm_bf16(
    const u16* __restrict__ A, int lda,
    const u16* __restrict__ Bt, const float* __restrict__ bias,
    u16* __restrict__ C, int M, int N, int K)
{
    __shared__ __align__(16) u16 As[128 * 64];
    __shared__ __align__(16) u16 Bs[128 * 64];

    const int bm = blockIdx.x * 128;
    const int bn = blockIdx.y * 128;

    const int tid = threadIdx.x;
    const int wv = tid >> 6;
    const int lane = tid & 63;
    const int wr = wv >> 1;
    const int wc = wv & 1;

    const int lrow = lane >> 3;
    const int lcol = (lane & 7) << 3;

    f32x4 acc[4][4];
#pragma unroll
    for (int i = 0; i < 4; ++i)
#pragma unroll
        for (int j = 0; j < 4; ++j) acc[i][j] = (f32x4){0.f, 0.f, 0.f, 0.f};

    for (int k0 = 0; k0 < K; k0 += 64) {
#pragma unroll
        for (int q = 0; q < 4; ++q) {
            const int c = wv * 4 + q;
            const int row = c * 8 + lrow;
            gload_lds16(&A[(size_t)(bm + row) * lda + k0 + lcol], &As[c * 512]);
            gload_lds16(&Bt[(size_t)(bn + row) * K + k0 + lcol], &Bs[c * 512]);
        }
        __syncthreads();

#pragma unroll
        for (int ks = 0; ks < 64; ks += 32) {
            int kk = ks + (lane >> 4) * 8;
            bf16x8 af[4], bfr[4];
#pragma unroll
            for (int i = 0; i < 4; ++i)
                af[i] = *reinterpret_cast<const bf16x8*>(&As[(wr * 64 + i * 16 + (lane & 15)) * 64 + kk]);
#pragma unroll
            for (int j = 0; j < 4; ++j)
                bfr[j] = *reinterpret_cast<const bf16x8*>(&Bs[(wc * 64 + j * 16 + (lane & 15)) * 64 + kk]);
#pragma unroll
            for (int i = 0; i < 4; ++i)
#pragma unroll
                for (int j = 0; j < 4; ++j)
                    acc[i][j] = __builtin_amdgcn_mfma_f32_16x16x32_bf16(af[i], bfr[j], acc[i][j], 0, 0, 0);
        }
        __syncthreads();
    }

    const int r4 = (lane >> 4) * 4;
    const int cn = lane & 15;
#pragma unroll
    for (int i = 0; i < 4; ++i) {
#pragma unroll
        for (int j = 0; j < 4; ++j) {
            int gcol = bn + wc * 64 + j * 16 + cn;
            float bsv = bias[gcol];
#pragma unroll
            for (int r = 0; r < 4; ++r) {
                int grow = bm + wr * 64 + i * 16 + r4 + r;
                C[(size_t)grow * N + gcol] = f2bf(acc[i][j][r] + bsv);
            }
        }
    }
}

// ---------------------------------------------------------------------------
// decode3: the fused 3-step autoregressive decode. One block = 64 rows.
// Per step: [H1 phase: all threads compute H1 into swizzled LDS]
//           [H2+head: 16 waves x (4 row-frag, 3 col-frag) MFMA, B from L2;
//            gelu+head-dot folded into the accumulator readout]
//           [tail: wave 0, 64 lanes = 64 rows, loss+state update in LDS]
// State/H1/H2 never touch global memory.
// ---------------------------------------------------------------------------

template<int NS>
__device__ inline void h1_phase(
    const float* __restrict__ wsrc, int cw0, int rh, int row0,
    const u16* __restrict__ Z, int gcol0, char* h1base,
    const float (*state)[20], const int* rid)
{
    float w[NS + 3][2];
#pragma unroll
    for (int r = 0; r < NS + 3; ++r) {
        float2 v = *reinterpret_cast<const float2*>(&wsrc[(size_t)r * 512 + cw0]);
        w[r][0] = v.x; w[r][1] = v.y;
    }
#pragma unroll 4
    for (int r = 0; r < 32; ++r) {
        const int row = rh * 32 + r;
        const int ridx = rid[row];
        float s[NS];
        if constexpr (NS == 6) {
            float4 a = *reinterpret_cast<const float4*>(&state[row][0]);
            float2 b = *reinterpret_cast<const float2*>(&state[row][4]);
            s[0] = a.x; s[1] = a.y; s[2] = a.z; s[3] = a.w; s[4] = b.x; s[5] = b.y;
        } else {
            float4 a = *reinterpret_cast<const float4*>(&state[row][8]);
            float4 b = *reinterpret_cast<const float4*>(&state[row][12]);
            float4 c = *reinterpret_cast<const float4*>(&state[row][16]);
            s[0] = a.x; s[1] = a.y; s[2]  = a.z; s[3]  = a.w;
            s[4] = b.x; s[5] = b.y; s[6]  = b.z; s[7]  = b.w;
            s[8] = c.x; s[9] = c.y; s[10] = c.z; s[11] = c.w;
        }
        u16x2 z = *reinterpret_cast<const u16x2*>(&Z[(size_t)(row0 + row) * 1024 + gcol0]);
        float d0 = (ridx == 0) ? w[NS][0] : ((ridx == 1) ? w[NS + 1][0] : w[NS + 2][0]);
        float d1 = (ridx == 0) ? w[NS][1] : ((ridx == 1) ? w[NS + 1][1] : w[NS + 2][1]);
#pragma unroll
        for (int j = 0; j < NS; ++j) { d0 += s[j] * w[j][0]; d1 += s[j] * w[j][1]; }
        float h0 = gelu_exact(bf2f(z[0]) + d0);
        float h1 = gelu_exact(bf2f(z[1]) + d1);
        unsigned int packed = (unsigned int)f2bf(h0) | ((unsigned int)f2bf(h1) << 16);
        int byte = (row * 2048 + gcol0 * 2) ^ ((row & 7) << 4);
        *reinterpret_cast<unsigned int*>(h1base + byte) = packed;
    }
}

__global__ __launch_bounds__(1024, 4) void decode3(
    const u16* __restrict__ Z,
    const float* __restrict__ pw1s, const float* __restrict__ fw1s,
    const u16* __restrict__ W2T, const float* __restrict__ bias2,
    const float* __restrict__ pw3, const float* __restrict__ pb3,
    const float* __restrict__ fw3, const float* __restrict__ fb3,
    const float* __restrict__ freq, const float* __restrict__ presv,
    const float* __restrict__ enrich, const int* __restrict__ round_mask,
    const int* __restrict__ perm_idx,
    float* __restrict__ part, float* __restrict__ out)
{
    __shared__ __align__(16) u16 H1s[64 * 1024];   // 128 KB, XOR-swizzled
    __shared__ float redh[16][64][3];              // 12 KB
    __shared__ __align__(16) float state_s[64][20];// [0:6) pres, [8:20) full
    __shared__ int pidx_s[64];
    __shared__ int rid_s[64];

    const int tid = threadIdx.x;
    const int wv  = tid >> 6;
    const int l   = tid & 63;
    const int row0 = blockIdx.x * 64;

    // ---- init ----
    {
        float* ss = &state_s[0][0];
        for (int i = tid; i < 64 * 20; i += 1024) ss[i] = 0.f;
        if (tid < 64) {
            int pp = perm_idx[row0 + tid];
            pidx_s[tid] = pp;
            rid_s[tid] = PERMS_C[pp][0];
        }
    }
    __syncthreads();

    // H1-phase thread geometry
    const int ci   = tid & 511;       // column pair index (0..511)
    const int rh   = tid >> 9;        // row half (0/1)
    const int half = ci >> 8;         // 0 = pres cols, 1 = full cols
    const int cw0  = (ci & 255) * 2;  // col within half
    const int gcol0 = ci * 2;         // global H1 col
    char* h1base = reinterpret_cast<char*>(H1s);

    // H2-phase wave geometry: wave wv covers cols [wv*48, wv*48+48)
    const int colbase = wv * 48;
    const bool needP = (colbase < 256);
    const bool needF = (colbase + 32) >= 256;

    float lf_acc = 0.f, bce_acc = 0.f, le_acc = 0.f, mm_acc = 0.f;

#pragma unroll 1
    for (int step = 0; step < 3; ++step) {
        // ---------------- H1 phase ----------------
        if (half == 0)
            h1_phase<6>(pw1s, cw0, rh, row0, Z, gcol0, h1base, state_s, rid_s);
        else
            h1_phase<12>(fw1s, cw0, rh, row0, Z, gcol0, h1base, state_s, rid_s);
        __syncthreads();

        // ---------------- H2 GEMM ----------------
        f32x4 acc[4][3];
#pragma unroll
        for (int rf = 0; rf < 4; ++rf)
#pragma unroll
            for (int cf = 0; cf < 3; ++cf) acc[rf][cf] = (f32x4){0.f, 0.f, 0.f, 0.f};

        const int ar = l & 15;
        const int ks = (l >> 4) * 8;
#pragma unroll 2
        for (int kf = 0; kf < 16; ++kf) {
            bf16x8 bfr[3];
#pragma unroll
            for (int cf = 0; cf < 3; ++cf) {
                int col = colbase + cf * 16 + ar;
                bfr[cf] = *reinterpret_cast<const bf16x8*>(&W2T[(size_t)col * 512 + kf * 32 + ks]);
            }
            bf16x8 afP[4], afF[4];
            if (needP) {
#pragma unroll
                for (int rf = 0; rf < 4; ++rf) {
                    int row = rf * 16 + ar;
                    int byte = (row * 2048 + (kf * 32 + ks) * 2) ^ ((row & 7) << 4);
                    afP[rf] = *reinterpret_cast<const bf16x8*>(h1base + byte);
                }
            }
            if (needF) {
#pragma unroll
                for (int rf = 0; rf < 4; ++rf) {
                    int row = rf * 16 + ar;
                    int byte = (row * 2048 + 1024 + (kf * 32 + ks) * 2) ^ ((row & 7) << 4);
                    afF[rf] = *reinterpret_cast<const bf16x8*>(h1base + byte);
                }
            }
#pragma unroll
            for (int cf = 0; cf < 3; ++cf) {
                const bool hf = (colbase + cf * 16) >= 256;
#pragma unroll
                for (int rf = 0; rf < 4; ++rf)
                    acc[rf][cf] = __builtin_amdgcn_mfma_f32_16x16x32_bf16(
                        hf ? afF[rf] : afP[rf], bfr[cf], acc[rf][cf], 0, 0, 0);
            }
        }

        // ---------------- head readout ----------------
#pragma unroll
        for (int rf = 0; rf < 4; ++rf) {
            float hsp[4] = {0.f, 0.f, 0.f, 0.f};
            float hsf[4] = {0.f, 0.f, 0.f, 0.f};
            float hse[4] = {0.f, 0.f, 0.f, 0.f};
#pragma unroll
            for (int cf = 0; cf < 3; ++cf) {
                const int colc = colbase + cf * 16;
                const int col = colc + ar;
                const float b2 = bias2[col];
                if (colc < 256) {
                    const float w3 = pw3[col];
#pragma unroll
                    for (int g = 0; g < 4; ++g) {
                        float h = gelu_exact(acc[rf][cf][g] + b2);
                        hsp[g] += h * w3;
                    }
                } else {
                    const float wf = fw3[(col - 256) * 2];
                    const float we = fw3[(col - 256) * 2 + 1];
#pragma unroll
                    for (int g = 0; g < 4; ++g) {
                        float h = gelu_exact(acc[rf][cf][g] + b2);
                        hsf[g] += h * wf;
                        hse[g] += h * we;
                    }
                }
            }
#pragma unroll
            for (int g = 0; g < 4; ++g) {
                float a = hsp[g], b = hsf[g], c = hse[g];
#pragma unroll
                for (int m = 1; m < 16; m <<= 1) {
                    a += __shfl_xor(a, m);
                    b += __shfl_xor(b, m);
                    c += __shfl_xor(c, m);
                }
                if ((l & 15) == 0) {
                    int row = rf * 16 + (l >> 4) * 4 + g;
                    redh[wv][row][0] = a;
                    redh[wv][row][1] = b;
                    redh[wv][row][2] = c;
                }
            }
        }
        __syncthreads();

        // ---------------- tail (wave 0) ----------------
        if (wv == 0) {
            const int row = l;
            const int b = row0 + row;
            float sp = 0.f, sf = 0.f, se = 0.f;
#pragma unroll
            for (int w2 = 0; w2 < 16; ++w2) {
                sp += redh[w2][row][0];
                sf += redh[w2][row][1];
                se += redh[w2][row][2];
            }
            float logit = sp + pb3[0];
            float pf    = sf + fb3[0];
            float pe    = se + fb3[1];
            int ridx = rid_s[row];
            float gt_f = freq[b * 3 + ridx];
            float gt_p = presv[b * 3 + ridx];
            float gt_e = enrich[b * 3 + ridx];
            float m = (float)round_mask[b * 3 + ridx];
            lf_acc  += (pf - gt_f) * (pf - gt_f) * m;
            bce_acc += (fmaxf(logit, 0.f) - logit * gt_p + log1pf(expf(-fabsf(logit)))) * m;
            le_acc  += (pe - gt_e) * (pe - gt_e) * m;
            mm_acc  += m;
            bool msk = m > 0.5f;
            float act_f = msk ? fminf(fmaxf(pf, -10.f), 10.f) : gt_f;
            float act_p = msk ? 1.f / (1.f + expf(-logit)) : gt_p;
            float act_e = msk ? fminf(fmaxf(pe, -100.f), 100.f) : gt_e;
            state_s[row][ridx * 2 + 0] = act_p;
            state_s[row][ridx * 2 + 1] = 1.f;
            state_s[row][8 + ridx * 4 + 0] = act_f;
            state_s[row][8 + ridx * 4 + 1] = act_p;
            state_s[row][8 + ridx * 4 + 2] = act_e;
            state_s[row][8 + ridx * 4 + 3] = 1.f;
            out[3 + b * 3 + ridx] = act_f;
            out[3 + 3 * BATCH + b * 3 + ridx] = act_p;
            out[3 + 6 * BATCH + b * 3 + ridx] = act_e;
            if (step < 2) rid_s[row] = PERMS_C[pidx_s[row]][step + 1];
        }
        __syncthreads();
    }

    // ---- per-block loss partials ----
    if (wv == 0) {
        for (int off = 32; off > 0; off >>= 1) {
            lf_acc  += __shfl_down(lf_acc, off);
            bce_acc += __shfl_down(bce_acc, off);
            le_acc  += __shfl_down(le_acc, off);
            mm_acc  += __shfl_down(mm_acc, off);
        }
        if (l == 0) {
            float4 v; v.x = lf_acc; v.y = bce_acc; v.z = le_acc; v.w = mm_acc;
            *reinterpret_cast<float4*>(&part[blockIdx.x * 4]) = v;
        }
    }
}

#define NPART (BATCH / 64)

__global__ __launch_bounds__(256) void finalize_kernel(
    const float* __restrict__ part, float* __restrict__ out)
{
    __shared__ float red[4][4];
    float a0 = 0.f, a1 = 0.f, a2 = 0.f, a3 = 0.f;
    for (int j = threadIdx.x; j < NPART; j += 256) {
        float4 v = *reinterpret_cast<const float4*>(&part[j * 4]);
        a0 += v.x; a1 += v.y; a2 += v.z; a3 += v.w;
    }
    for (int off = 32; off > 0; off >>= 1) {
        a0 += __shfl_down(a0, off);
        a1 += __shfl_down(a1, off);
        a2 += __shfl_down(a2, off);
        a3 += __shfl_down(a3, off);
    }
    const int wid = threadIdx.x >> 6, lane = threadIdx.x & 63;
    if (lane == 0) { red[wid][0] = a0; red[wid][1] = a1; red[wid][2] = a2; red[wid][3] = a3; }
    __syncthreads();
    if (threadIdx.x == 0) {
        float s0 = 0.f, s1 = 0.f, s2 = 0.f, s3 = 0.f;
#pragma unroll
        for (int w2 = 0; w2 < 4; ++w2) {
            s0 += red[w2][0]; s1 += red[w2][1]; s2 += red[w2][2]; s3 += red[w2][3];
        }
        float nm = s3 + 1e-8f;
        out[0] = s0 / nm;
        out[1] = s1 / nm;
        out[2] = s2 / nm;
    }
}

// ---------------------------------------------------------------------------
extern "C" void kernel_launch(void* const* d_in, const int* in_sizes, int n_in,
                              void* d_out, int out_size, void* d_ws, size_t ws_size,
                              hipStream_t stream)
{
    const float* seq       = (const float*)d_in[0];
    const float* freq      = (const float*)d_in[1];
    const float* presv     = (const float*)d_in[2];
    const float* enrich    = (const float*)d_in[3];
    const float* pw1       = (const float*)d_in[4];
    const float* pb1       = (const float*)d_in[5];
    const float* pw2       = (const float*)d_in[6];
    const float* pb2       = (const float*)d_in[7];
    const float* pw3       = (const float*)d_in[8];
    const float* pb3       = (const float*)d_in[9];
    const float* fw1       = (const float*)d_in[10];
    const float* fb1       = (const float*)d_in[11];
    const float* fw2       = (const float*)d_in[12];
    const float* fb2       = (const float*)d_in[13];
    const float* fw3       = (const float*)d_in[14];
    const float* fb3       = (const float*)d_in[15];
    const int*   perm_idx  = (const int*)d_in[16];
    const int*   round_mask= (const int*)d_in[17];
    float* out = (float*)d_out;

    char* w = (char*)d_ws;
    u16* sb  = (u16*)w;  w += (size_t)BATCH * 512 * 2;   // 16 MB
    u16* Z   = (u16*)w;  w += (size_t)BATCH * 1024 * 2;  // 32 MB
    u16* W1T = (u16*)w;  w += (size_t)1024 * 512 * 2;
    u16* W2T = (u16*)w;  w += (size_t)768 * 512 * 2;
    float* bias1 = (float*)w; w += 1024 * 4;
    float* bias2 = (float*)w; w += 768 * 4;
    float* part  = (float*)w;

    // prep
    {
        const int total = BATCH * 512 + 1024 * 512 + 768 * 512 + 1024 + 768;
        int grid = (total + 255) / 256;
        prep_kernel<<<grid, 256, 0, stream>>>(seq, pw1, pw2, fw1, fw2, pb1, pb2, fb1, fb2,
                                              sb, W1T, W2T, bias1, bias2);
    }

    // Z = seq @ [pw1[:512] | fw1[:512]] + bias1   (M=16384, N=1024, K=512)
    gemm_bf16<<<dim3(BATCH / 128, 1024 / 128), 256, 0, stream>>>(
        sb, 512, W1T, bias1, Z, BATCH, 1024, 512);

    // fused 3-step decode
    decode3<<<NPART, 1024, 0, stream>>>(
        Z, pw1 + (size_t)512 * 512, fw1 + (size_t)512 * 512,
        W2T, bias2, pw3, pb3, fw3, fb3,
        freq, presv, enrich, round_mask, perm_idx, part, out);

    finalize_kernel<<<1, 256, 0, stream>>>(part, out);
}